// Round 9
// baseline (58.079 us; speedup 1.0000x reference)
//
#include <hip/hip_runtime.h>

#define NB 2048
#define NC 16
#define ND 256
#define OUTW 353
#define THRED 0.8f

typedef short bf16x8 __attribute__((ext_vector_type(8)));
typedef float f32x4 __attribute__((ext_vector_type(4)));
typedef float f32x4a __attribute__((ext_vector_type(4), aligned(4)));

__device__ __forceinline__ short f2s(float x) {      // native cast -> v_cvt_pk_bf16_f32
    __bf16 h = (__bf16)x;
    return __builtin_bit_cast(short, h);
}

__device__ __forceinline__ bf16x8 cvt8(const float4& a, const float4& b) {
    bf16x8 r;
    r[0] = f2s(a.x); r[1] = f2s(a.y); r[2] = f2s(a.z); r[3] = f2s(a.w);
    r[4] = f2s(b.x); r[5] = f2s(b.y); r[6] = f2s(b.z); r[7] = f2s(b.w);
    return r;
}

__device__ __forceinline__ float dot8(const float4& a, const float4& b) {
    float sq = 0.f;
    sq = fmaf(a.x, a.x, sq); sq = fmaf(a.y, a.y, sq);
    sq = fmaf(a.z, a.z, sq); sq = fmaf(a.w, a.w, sq);
    sq = fmaf(b.x, b.x, sq); sq = fmaf(b.y, b.y, sq);
    sq = fmaf(b.z, b.z, sq); sq = fmaf(b.w, b.w, sq);
    return sq;
}

// One block (512 thr = 8 waves) per b. Wave q owns K-slice [32q, 32q+32):
// per tile per lane that's 8 contiguous floats = 2 float4, so ALL 7 tiles fit
// in 56 VGPRs -> single burst, one latency exposure, no spill risk (R8 lesson).
// Partial acc/ssq parked in LDS as XOR-swizzled float4 chunks (conflict-free),
// wave 0 combines and runs the slim two-pass sim epilogue (R7 lesson).
__global__ __launch_bounds__(512, 4) void fused_kernel(const float* __restrict__ e,
                                                       const int* __restrict__ nm,
                                                       float* __restrict__ out) {
    __shared__ __align__(16) float red[8][64][32];   // 64 KB -> 2 blocks/CU

    const int bid = blockIdx.x;
    const int b   = (bid & 7) * 256 + (bid >> 3);    // XCD-chunked, bijective
    const int q   = threadIdx.x >> 6;                // K-slice id 0..7
    const int l   = threadIdx.x & 63;
    const int col = l & 15, hi = l >> 4;
    const int koff = q * 32 + hi * 8;                // this lane's 8 dims
    const int sw  = l & 7;                           // LDS chunk swizzle key

    // ---- clamped neighbor indices + effective cumulative masks (per lane col) ----
    const int bm1 = (b >= 1) ? b - 1 : 0;
    const int bm2 = (b >= 2) ? b - 2 : 0;
    const int bm3 = (b >= 3) ? b - 3 : 0;
    const int bp1 = (b + 1 < NB) ? b + 1 : NB - 1;
    const int bp2 = (b + 2 < NB) ? b + 2 : NB - 1;
    const int bp3 = (b + 3 < NB) ? b + 3 : NB - 1;

    const float a1 = (b >= 1) ? (float)nm[bm1 * NC + col] : 0.f;
    const float a2 = (b >= 2) ? (float)nm[bm2 * NC + col] : 0.f;
    const float a3 = (b >= 3) ? (float)nm[bm3 * NC + col] : 0.f;
    const float r0 = (float)nm[b * NC + col];
    const float r1 = (b + 1 < NB) ? (float)nm[bp1 * NC + col] : 0.f;
    const float r2 = (b + 2 < NB) ? (float)nm[bp2 * NC + col] : 0.f;

    float em[6];
    em[0] = a1;
    em[1] = a1 * a2;
    em[2] = a1 * a2 * a3;
    em[3] = (b + 1 < NB) ? r0 : 0.f;
    em[4] = (b + 2 < NB) ? r0 * r1 : 0.f;
    em[5] = (b + 3 < NB) ? r0 * r1 * r2 : 0.f;

    const int gbs[6] = {bm1, bm2, bm3, bp1, bp2, bp3};

    // ================= burst: 7 tiles x 2 float4 = 14 independent loads =================
    const float* rp0 = e + ((size_t)b * NC + col) * ND + koff;
    float4 s0 = *reinterpret_cast<const float4*>(rp0);
    float4 s1 = *reinterpret_cast<const float4*>(rp0 + 4);

    float4 t0[6], t1[6];
#pragma unroll
    for (int p = 0; p < 6; ++p) {
        const float* rp = e + ((size_t)gbs[p] * NC + col) * ND + koff;
        t0[p] = *reinterpret_cast<const float4*>(rp);
        t1[p] = *reinterpret_cast<const float4*>(rp + 4);
    }
    __builtin_amdgcn_sched_barrier(0);   // all 14 loads issued before compute

    // ---- own slice: A-frag + ssq partial ----
    bf16x8 af = cvt8(s0, s1);
    const float ssq_own = dot8(s0, s1);

    // ---- 6 neighbors: 1 MFMA each + ssq + masked neigh accum ----
    float sqv[6];
    float nacc[8];
#pragma unroll
    for (int k = 0; k < 8; ++k) nacc[k] = 0.f;

#pragma unroll
    for (int p = 0; p < 6; ++p) {
        bf16x8 bf = cvt8(t0[p], t1[p]);
        f32x4 ac = (f32x4){0.f, 0.f, 0.f, 0.f};
        ac = __builtin_amdgcn_mfma_f32_16x16x32_bf16(af, bf, ac, 0, 0, 0);
        *reinterpret_cast<f32x4*>(&red[q][l][(p ^ sw) * 4]) = ac;   // park, swizzled

        sqv[p] = dot8(t0[p], t1[p]);

        const float m = em[p];
        nacc[0] = fmaf(m, t0[p].x, nacc[0]); nacc[1] = fmaf(m, t0[p].y, nacc[1]);
        nacc[2] = fmaf(m, t0[p].z, nacc[2]); nacc[3] = fmaf(m, t0[p].w, nacc[3]);
        nacc[4] = fmaf(m, t1[p].x, nacc[4]); nacc[5] = fmaf(m, t1[p].y, nacc[5]);
        nacc[6] = fmaf(m, t1[p].z, nacc[6]); nacc[7] = fmaf(m, t1[p].w, nacc[7]);
    }
    {
        f32x4 c6 = (f32x4){ssq_own, sqv[0], sqv[1], sqv[2]};
        f32x4 c7 = (f32x4){sqv[3], sqv[4], sqv[5], 0.f};
        *reinterpret_cast<f32x4*>(&red[q][l][(6 ^ sw) * 4]) = c6;
        *reinterpret_cast<f32x4*>(&red[q][l][(7 ^ sw) * 4]) = c7;
    }

    // ---- neigh store: lane owns row `col`, dims [koff, koff+8) ----
    {
        const float s6 = 1.0f / 6.0f;
        float* nrow = out + (size_t)(b * NC + col) * OUTW + koff;
        f32x4 v;
        v[0] = nacc[0] * s6; v[1] = nacc[1] * s6; v[2] = nacc[2] * s6; v[3] = nacc[3] * s6;
        *reinterpret_cast<f32x4a*>(nrow) = v;
        v[0] = nacc[4] * s6; v[1] = nacc[5] * s6; v[2] = nacc[6] * s6; v[3] = nacc[7] * s6;
        *reinterpret_cast<f32x4a*>(nrow + 4) = v;
    }

    __syncthreads();
    if (q != 0) return;

    // ================= wave-0 epilogue =================
    // ssq combine (chunks 6,7 across 8 waves)
    f32x4 sm6 = (f32x4){0.f, 0.f, 0.f, 0.f};
    f32x4 sm7 = (f32x4){0.f, 0.f, 0.f, 0.f};
#pragma unroll
    for (int w = 0; w < 8; ++w) {
        sm6 += *reinterpret_cast<const f32x4*>(&red[w][l][(6 ^ sw) * 4]);
        sm7 += *reinterpret_cast<const f32x4*>(&red[w][l][(7 ^ sw) * 4]);
    }
    float norms[7];
#pragma unroll
    for (int tt = 0; tt < 7; ++tt) {
        float v = (tt < 4) ? sm6[tt] : sm7[tt - 4];
        v += __shfl_xor(v, 16, 64);
        v += __shfl_xor(v, 32, 64);
        norms[tt] = sqrtf(v);
    }
    float na[4];
#pragma unroll
    for (int r = 0; r < 4; ++r) na[r] = __shfl(norms[0], hi * 4 + r, 16);

    // acc combine (chunks 0..5 across 8 waves)
    f32x4 acc[6];
#pragma unroll
    for (int p = 0; p < 6; ++p) {
        f32x4 s = (f32x4){0.f, 0.f, 0.f, 0.f};
#pragma unroll
        for (int w = 0; w < 8; ++w)
            s += *reinterpret_cast<const f32x4*>(&red[w][l][(p ^ sw) * 4]);
        acc[p] = s;
    }

    // pass 1: rowsum -> inv
    float rowsum[4] = {0.f, 0.f, 0.f, 0.f};
#pragma unroll
    for (int p = 0; p < 6; ++p) {
        const bool mv = (em[p] != 0.f);
        const float nbv = norms[1 + p];
#pragma unroll
        for (int r = 0; r < 4; ++r) {
            float qd = acc[p][r] / fmaxf(na[r] * nbv, 1e-8f);
            rowsum[r] += (mv && qd > THRED) ? fminf(qd, 1.f) : 0.f;
        }
    }
#pragma unroll
    for (int r = 0; r < 4; ++r) {
#pragma unroll
        for (int o = 1; o < 16; o <<= 1) rowsum[r] += __shfl_xor(rowsum[r], o, 16);
        rowsum[r] = 1.0f / fmaxf(rowsum[r] + 1.0f, 1e-12f);
    }

    // pass 2: recompute sims, scale, store
#pragma unroll
    for (int r = 0; r < 4; ++r) {
        float* orow = out + (size_t)(b * NC + hi * 4 + r) * OUTW;
#pragma unroll
        for (int p = 0; p < 6; ++p) {
            const bool mv = (em[p] != 0.f);
            float qd = acc[p][r] / fmaxf(na[r] * norms[1 + p], 1e-8f);
            float sv = (mv && qd > THRED) ? fminf(qd, 1.f) : 0.f;
            orow[ND + p * NC + col] = sv * rowsum[r];
        }
        if (col == 0) orow[ND + 96] = rowsum[r];
    }
}

extern "C" void kernel_launch(void* const* d_in, const int* in_sizes, int n_in,
                              void* d_out, int out_size, void* d_ws, size_t ws_size,
                              hipStream_t stream) {
    const float* e = (const float*)d_in[0];
    const int* nmv = (const int*)d_in[1];
    float* out     = (float*)d_out;
    fused_kernel<<<NB, 512, 0, stream>>>(e, nmv, out);
}

// Round 10
// 44.402 us; speedup vs baseline: 1.3080x; 1.3080x over previous
//
#include <hip/hip_runtime.h>

#define NB 2048
#define NC 16
#define ND 256
#define OUTW 353
#define THRED 0.8f

typedef short bf16x8 __attribute__((ext_vector_type(8)));
typedef float f32x4 __attribute__((ext_vector_type(4)));
typedef float f32x4a __attribute__((ext_vector_type(4), aligned(4)));

__device__ __forceinline__ short f2s(float x) {      // native cast -> v_cvt_pk_bf16_f32
    __bf16 h = (__bf16)x;
    return __builtin_bit_cast(short, h);
}

__device__ __forceinline__ bf16x8 cvt8(const float4& a, const float4& b) {
    bf16x8 r;
    r[0] = f2s(a.x); r[1] = f2s(a.y); r[2] = f2s(a.z); r[3] = f2s(a.w);
    r[4] = f2s(b.x); r[5] = f2s(b.y); r[6] = f2s(b.z); r[7] = f2s(b.w);
    return r;
}

__device__ __forceinline__ float ssq16(const float4& a, const float4& b,
                                       const float4& c, const float4& d) {
    float sq = 0.f;
    sq = fmaf(a.x, a.x, sq); sq = fmaf(a.y, a.y, sq);
    sq = fmaf(a.z, a.z, sq); sq = fmaf(a.w, a.w, sq);
    sq = fmaf(b.x, b.x, sq); sq = fmaf(b.y, b.y, sq);
    sq = fmaf(b.z, b.z, sq); sq = fmaf(b.w, b.w, sq);
    sq = fmaf(c.x, c.x, sq); sq = fmaf(c.y, c.y, sq);
    sq = fmaf(c.z, c.z, sq); sq = fmaf(c.w, c.w, sq);
    sq = fmaf(d.x, d.x, sq); sq = fmaf(d.y, d.y, sq);
    sq = fmaf(d.z, d.z, sq); sq = fmaf(d.w, d.w, sq);
    return sq;
}

// One block (256 thr = 4 waves) per b; wave q owns K-quarter [64q, 64q+64).
// R10 = R7 + depth-2 software pipeline over the 6 neighbor tiles with
// hand-named register sets (no sched_barrier, no arrays): R8/R9 showed a full
// fence + big burst makes hipcc spill (WRITE_SIZE 72/107 MB); R7 showed no
// pipeline at all leaves 7 serial latency exposures (45us). Depth-2 keeps
// only 2 tiles (32 VGPR) in flight -> counted-vmcnt overlap without spills.
__global__ __launch_bounds__(256, 3) void fused_kernel(const float* __restrict__ e,
                                                       const int* __restrict__ nm,
                                                       float* __restrict__ out) {
    __shared__ float red[4][64][33];   // [wave][lane][24 acc + 7 ssq], odd stride

    const int bid = blockIdx.x;
    const int b   = (bid & 7) * 256 + (bid >> 3);    // XCD-chunked, bijective
    const int q   = threadIdx.x >> 6;                // K-quarter
    const int l   = threadIdx.x & 63;
    const int col = l & 15, hi = l >> 4;
    const int koff = q * 64 + hi * 8;                // chunk0; chunk1 at +32

    // ---- clamped neighbor indices + effective cumulative masks (per lane col) ----
    const int bm1 = (b >= 1) ? b - 1 : 0;
    const int bm2 = (b >= 2) ? b - 2 : 0;
    const int bm3 = (b >= 3) ? b - 3 : 0;
    const int bp1 = (b + 1 < NB) ? b + 1 : NB - 1;
    const int bp2 = (b + 2 < NB) ? b + 2 : NB - 1;
    const int bp3 = (b + 3 < NB) ? b + 3 : NB - 1;

    const float a1 = (b >= 1) ? (float)nm[bm1 * NC + col] : 0.f;
    const float a2 = (b >= 2) ? (float)nm[bm2 * NC + col] : 0.f;
    const float a3 = (b >= 3) ? (float)nm[bm3 * NC + col] : 0.f;
    const float r0 = (float)nm[b * NC + col];
    const float r1 = (b + 1 < NB) ? (float)nm[bp1 * NC + col] : 0.f;
    const float r2 = (b + 2 < NB) ? (float)nm[bp2 * NC + col] : 0.f;

    float em[6];
    em[0] = a1;
    em[1] = a1 * a2;
    em[2] = a1 * a2 * a3;
    em[3] = (b + 1 < NB) ? r0 : 0.f;
    em[4] = (b + 2 < NB) ? r0 * r1 : 0.f;
    em[5] = (b + 3 < NB) ? r0 * r1 * r2 : 0.f;

    const int gbs[6] = {bm1, bm2, bm3, bp1, bp2, bp3};

    float nacc[16];
#pragma unroll
    for (int k = 0; k < 16; ++k) nacc[k] = 0.f;
    float* myred = &red[q][l][0];

    // ---- prologue: load own tile + neighbor 0 (reg set A) ----
    const float* rp_own = e + ((size_t)b * NC + col) * ND + koff;
    float4 s0 = *reinterpret_cast<const float4*>(rp_own);
    float4 s1 = *reinterpret_cast<const float4*>(rp_own + 4);
    float4 s2 = *reinterpret_cast<const float4*>(rp_own + 32);
    float4 s3 = *reinterpret_cast<const float4*>(rp_own + 36);

    const float* rp = e + ((size_t)gbs[0] * NC + col) * ND + koff;
    float4 pA0 = *reinterpret_cast<const float4*>(rp);
    float4 pA1 = *reinterpret_cast<const float4*>(rp + 4);
    float4 pA2 = *reinterpret_cast<const float4*>(rp + 32);
    float4 pA3 = *reinterpret_cast<const float4*>(rp + 36);
    float4 pB0, pB1, pB2, pB3;

    // own-tile compute overlaps neighbor-0 latency
    bf16x8 af0 = cvt8(s0, s1);
    bf16x8 af1 = cvt8(s2, s3);
    myred[24] = ssq16(s0, s1, s2, s3);

#define LOADT(P, R0, R1, R2, R3)                                            \
    {                                                                       \
        const float* _rp = e + ((size_t)gbs[P] * NC + col) * ND + koff;     \
        R0 = *reinterpret_cast<const float4*>(_rp);                         \
        R1 = *reinterpret_cast<const float4*>(_rp + 4);                     \
        R2 = *reinterpret_cast<const float4*>(_rp + 32);                    \
        R3 = *reinterpret_cast<const float4*>(_rp + 36);                    \
    }

#define PROC(P, C0, C1, C2, C3)                                             \
    {                                                                       \
        bf16x8 bf0 = cvt8(C0, C1);                                          \
        bf16x8 bf1 = cvt8(C2, C3);                                          \
        f32x4 ac = (f32x4){0.f, 0.f, 0.f, 0.f};                             \
        ac = __builtin_amdgcn_mfma_f32_16x16x32_bf16(af0, bf0, ac, 0, 0, 0);\
        ac = __builtin_amdgcn_mfma_f32_16x16x32_bf16(af1, bf1, ac, 0, 0, 0);\
        myred[(P) * 4 + 0] = ac[0];                                         \
        myred[(P) * 4 + 1] = ac[1];                                         \
        myred[(P) * 4 + 2] = ac[2];                                         \
        myred[(P) * 4 + 3] = ac[3];                                         \
        myred[24 + 1 + (P)] = ssq16(C0, C1, C2, C3);                        \
        const float m = em[P];                                              \
        nacc[0]  = fmaf(m, C0.x, nacc[0]);  nacc[1]  = fmaf(m, C0.y, nacc[1]);  \
        nacc[2]  = fmaf(m, C0.z, nacc[2]);  nacc[3]  = fmaf(m, C0.w, nacc[3]);  \
        nacc[4]  = fmaf(m, C1.x, nacc[4]);  nacc[5]  = fmaf(m, C1.y, nacc[5]);  \
        nacc[6]  = fmaf(m, C1.z, nacc[6]);  nacc[7]  = fmaf(m, C1.w, nacc[7]);  \
        nacc[8]  = fmaf(m, C2.x, nacc[8]);  nacc[9]  = fmaf(m, C2.y, nacc[9]);  \
        nacc[10] = fmaf(m, C2.z, nacc[10]); nacc[11] = fmaf(m, C2.w, nacc[11]); \
        nacc[12] = fmaf(m, C3.x, nacc[12]); nacc[13] = fmaf(m, C3.y, nacc[13]); \
        nacc[14] = fmaf(m, C3.z, nacc[14]); nacc[15] = fmaf(m, C3.w, nacc[15]); \
    }

    // ---- depth-2 pipelined neighbor loop (alternating reg sets A/B) ----
    LOADT(1, pB0, pB1, pB2, pB3);  PROC(0, pA0, pA1, pA2, pA3);
    LOADT(2, pA0, pA1, pA2, pA3);  PROC(1, pB0, pB1, pB2, pB3);
    LOADT(3, pB0, pB1, pB2, pB3);  PROC(2, pA0, pA1, pA2, pA3);
    LOADT(4, pA0, pA1, pA2, pA3);  PROC(3, pB0, pB1, pB2, pB3);
    LOADT(5, pB0, pB1, pB2, pB3);  PROC(4, pA0, pA1, pA2, pA3);
                                   PROC(5, pB0, pB1, pB2, pB3);
#undef LOADT
#undef PROC

    // ---- neigh store: lane owns row `col`, dims koff..+7 and koff+32..+39 ----
    {
        const float s6 = 1.0f / 6.0f;
        float* nrow = out + (size_t)(b * NC + col) * OUTW + koff;
        f32x4 v;
        v[0] = nacc[0] * s6;  v[1] = nacc[1] * s6;  v[2] = nacc[2] * s6;  v[3] = nacc[3] * s6;
        *reinterpret_cast<f32x4a*>(nrow) = v;
        v[0] = nacc[4] * s6;  v[1] = nacc[5] * s6;  v[2] = nacc[6] * s6;  v[3] = nacc[7] * s6;
        *reinterpret_cast<f32x4a*>(nrow + 4) = v;
        v[0] = nacc[8] * s6;  v[1] = nacc[9] * s6;  v[2] = nacc[10] * s6; v[3] = nacc[11] * s6;
        *reinterpret_cast<f32x4a*>(nrow + 32) = v;
        v[0] = nacc[12] * s6; v[1] = nacc[13] * s6; v[2] = nacc[14] * s6; v[3] = nacc[15] * s6;
        *reinterpret_cast<f32x4a*>(nrow + 36) = v;
    }

    __syncthreads();
    if (q != 0) return;

    // ================= wave-0 epilogue (slim, two-pass; verbatim R7) =================
    float norms[7];
#pragma unroll
    for (int tt = 0; tt < 7; ++tt) {
        float v = red[0][l][24 + tt] + red[1][l][24 + tt]
                + red[2][l][24 + tt] + red[3][l][24 + tt];
        v += __shfl_xor(v, 16, 64);
        v += __shfl_xor(v, 32, 64);
        norms[tt] = sqrtf(v);
    }
    float na[4];
#pragma unroll
    for (int r = 0; r < 4; ++r) na[r] = __shfl(norms[0], hi * 4 + r, 16);

    float acc[24];
#pragma unroll
    for (int k = 0; k < 24; ++k)
        acc[k] = red[0][l][k] + red[1][l][k] + red[2][l][k] + red[3][l][k];

    float rowsum[4] = {0.f, 0.f, 0.f, 0.f};
#pragma unroll
    for (int p = 0; p < 6; ++p) {
        const bool mv = (em[p] != 0.f);
        const float nbv = norms[1 + p];
#pragma unroll
        for (int r = 0; r < 4; ++r) {
            float qd = acc[p * 4 + r] / fmaxf(na[r] * nbv, 1e-8f);
            rowsum[r] += (mv && qd > THRED) ? fminf(qd, 1.f) : 0.f;
        }
    }
#pragma unroll
    for (int r = 0; r < 4; ++r) {
#pragma unroll
        for (int o = 1; o < 16; o <<= 1) rowsum[r] += __shfl_xor(rowsum[r], o, 16);
        rowsum[r] = 1.0f / fmaxf(rowsum[r] + 1.0f, 1e-12f);   // -> inv
    }

#pragma unroll
    for (int r = 0; r < 4; ++r) {
        float* orow = out + (size_t)(b * NC + hi * 4 + r) * OUTW;
#pragma unroll
        for (int p = 0; p < 6; ++p) {
            const bool mv = (em[p] != 0.f);
            float qd = acc[p * 4 + r] / fmaxf(na[r] * norms[1 + p], 1e-8f);
            float sv = (mv && qd > THRED) ? fminf(qd, 1.f) : 0.f;
            orow[ND + p * NC + col] = sv * rowsum[r];
        }
        if (col == 0) orow[ND + 96] = rowsum[r];
    }
}

extern "C" void kernel_launch(void* const* d_in, const int* in_sizes, int n_in,
                              void* d_out, int out_size, void* d_ws, size_t ws_size,
                              hipStream_t stream) {
    const float* e = (const float*)d_in[0];
    const int* nmv = (const int*)d_in[1];
    float* out     = (float*)d_out;
    fused_kernel<<<NB, 256, 0, stream>>>(e, nmv, out);
}